// Round 4
// baseline (3276.965 us; speedup 1.0000x reference)
//
#include <hip/hip_runtime.h>
#include <hip/hip_bf16.h>

#define NPB 8192
#define NB 8
#define MQ 2048
#define FD 64
#define KN 32
#define CD 128
#define NQ (NB*MQ)
#define CAP 512

typedef unsigned long long ull;

// exact (non-FMA) squared distance, matching ((dx*dx + dy*dy) + dz*dz) in f32
__device__ __forceinline__ float dist2(float ax, float ay, float az,
                                       float bx, float by, float bz) {
    float dx = __fsub_rn(ax, bx);
    float dy = __fsub_rn(ay, by);
    float dz = __fsub_rn(az, bz);
    return __fadd_rn(__fadd_rn(__fmul_rn(dx, dx), __fmul_rn(dy, dy)), __fmul_rn(dz, dz));
}

// ---------------- FPS: one block per cloud, 1024 threads, 8 pts/thread ----------------
__global__ __launch_bounds__(1024) void fps_kernel(const float* __restrict__ pos_in,
                                                   int* __restrict__ samp) {
    const int b = blockIdx.x;
    const int tid = threadIdx.x;
    __shared__ float sx[NPB], sy[NPB], sz[NPB];   // 96 KB
    __shared__ ull part[16];
    __shared__ ull sbest;

    float px[8], py[8], pz[8], dmin[8];
    const float* p0 = pos_in + (size_t)b * NPB * 3;
    #pragma unroll
    for (int j = 0; j < 8; j++) {
        int p = j * 1024 + tid;
        float x = p0[p * 3 + 0];
        float y = p0[p * 3 + 1];
        float z = p0[p * 3 + 2];
        sx[p] = x; sy[p] = y; sz[p] = z;
        px[j] = x; py[j] = y; pz[j] = z;
        dmin[j] = INFINITY;
    }
    __syncthreads();

    int last = 0;
    for (int t = 0; t < MQ; t++) {
        if (tid == 0) samp[b * MQ + t] = last;
        float lx = sx[last], ly = sy[last], lz = sz[last];
        float bd = -1.0f;
        int bi = 0;
        #pragma unroll
        for (int j = 0; j < 8; j++) {
            float d = dist2(px[j], py[j], pz[j], lx, ly, lz);
            float dm = fminf(dmin[j], d);
            dmin[j] = dm;
            if (dm > bd) { bd = dm; bi = j * 1024 + tid; }  // strict >: lowest idx on tie
        }
        // key: max dmin, tie -> lowest index (via ~idx); dmin >= 0 so float bits monotonic
        ull key = ((ull)__float_as_uint(bd) << 32) | (unsigned int)(~bi);
        #pragma unroll
        for (int off = 32; off; off >>= 1) {
            ull o = __shfl_down(key, (unsigned)off, 64);
            key = (o > key) ? o : key;
        }
        if ((tid & 63) == 0) part[tid >> 6] = key;
        __syncthreads();
        if (tid < 64) {
            ull k2 = (tid < 16) ? part[tid] : 0ULL;
            #pragma unroll
            for (int off = 8; off; off >>= 1) {
                ull o = __shfl_down(k2, (unsigned)off, 64);
                k2 = (o > k2) ? o : k2;
            }
            if (tid == 0) sbest = k2;
        }
        __syncthreads();
        last = ((int)(~((unsigned int)sbest))) & (NPB - 1);
    }
}

// -------- Fused ball query + PointNet conv + maxpool: one block (128 thr) per query --------
__global__ __launch_bounds__(128) void qmlp_kernel(const float* __restrict__ xin,
                                                   const float* __restrict__ pos_in,
                                                   const int* __restrict__ samp,
                                                   const float* __restrict__ W1,
                                                   const float* __restrict__ b1,
                                                   float* __restrict__ out0) {
    const int q = blockIdx.x;
    const int tid = threadIdx.x;
    const int b = q >> 11;                       // q / MQ
    const float* P = pos_in + (size_t)b * NPB * 3;

    __shared__ ull buf[CAP];
    __shared__ int scnt;
    __shared__ int nb[KN];
    __shared__ int snk;
    __shared__ __align__(16) float msg[KN][68];

    const int s = samp[q] & (NPB - 1);
    const float qx = P[s * 3 + 0];
    const float qy = P[s * 3 + 1];
    const float qz = P[s * 3 + 2];
    const float RR = (float)(0.1 * 0.1);

    if (tid == 0) scnt = 0;
    __syncthreads();

    // ---- collect candidates within radius ----
    for (int p = tid; p < NPB; p += 128) {
        float x = P[p * 3 + 0];
        float y = P[p * 3 + 1];
        float z = P[p * 3 + 2];
        float d2 = dist2(qx, qy, qz, x, y, z);
        if (d2 <= RR) {
            int slot = atomicAdd(&scnt, 1);
            if (slot < CAP) {
                buf[slot] = ((ull)__float_as_uint(d2) << 32) | (unsigned int)p;
            }
        }
    }
    __syncthreads();

    // ---- wave 0 selects K smallest (d2, idx) keys; ties -> lower idx ----
    if (tid < 64) {
        int n = scnt; if (n > CAP) n = CAP;
        ull ck[CAP / 64];
        #pragma unroll
        for (int i = 0; i < CAP / 64; i++) {
            int sl = tid + i * 64;
            ck[i] = (sl < n) ? buf[sl] : ~0ULL;
        }
        const int nk = (n < KN) ? n : KN;
        for (int r = 0; r < nk; r++) {
            ull lm = ck[0];
            int li = 0;
            #pragma unroll
            for (int i = 1; i < CAP / 64; i++) {
                if (ck[i] < lm) { lm = ck[i]; li = i; }
            }
            ull gm = lm;
            #pragma unroll
            for (int off = 1; off < 64; off <<= 1) {
                ull o = __shfl_xor(gm, off, 64);
                gm = (o < gm) ? o : gm;
            }
            ull won = __ballot(lm == gm);
            int wlane = __ffsll((long long)won) - 1;
            if (tid == wlane) ck[li] = ~0ULL;
            if (tid == 0) nb[r] = ((int)(unsigned int)gm) & (NPB - 1);
        }
        if (tid == 0) snk = nk;
    }
    __syncthreads();

    const int n = snk;

    // ---- stage msg = [x_j (64), pos_j - pos_i (3), 0] into LDS ----
    const int lane64 = tid & 63, half = tid >> 6;
    for (int k = half; k < n; k += 2) {
        int p = nb[k];
        msg[k][lane64] = xin[((size_t)(b * NPB + p)) * FD + lane64];
    }
    if (tid < n) {   // n <= 32 <= 128
        int p = nb[tid];
        msg[tid][64] = __fsub_rn(P[p * 3 + 0], qx);
        msg[tid][65] = __fsub_rn(P[p * 3 + 1], qy);
        msg[tid][66] = __fsub_rn(P[p * 3 + 2], qz);
        msg[tid][67] = 0.0f;
    }

    // ---- per-thread output channel ----
    float w[68];
    #pragma unroll
    for (int f = 0; f < 67; f++) w[f] = W1[f * CD + tid];
    w[67] = 0.0f;
    const float bias = b1[tid];
    __syncthreads();

    float acc = 0.0f;  // relu >= 0 and n >= 1 (self), so 0 is identity for the max
    for (int k = 0; k < n; k++) {
        float s0 = 0.f, s1 = 0.f, s2 = 0.f, s3 = 0.f;
        #pragma unroll
        for (int f4 = 0; f4 < 17; f4++) {
            float4 mv = *(const float4*)&msg[k][f4 * 4];
            s0 = fmaf(mv.x, w[f4 * 4 + 0], s0);
            s1 = fmaf(mv.y, w[f4 * 4 + 1], s1);
            s2 = fmaf(mv.z, w[f4 * 4 + 2], s2);
            s3 = fmaf(mv.w, w[f4 * 4 + 3], s3);
        }
        float h = (s0 + s1) + (s2 + s3) + bias;
        h = fmaxf(h, 0.0f);
        acc = fmaxf(acc, h);
    }
    out0[(size_t)q * CD + tid] = acc;
}

// ---------------- qpos / batch / idx outputs (all float32) ----------------
__global__ __launch_bounds__(256) void tail_kernel(const float* __restrict__ pos_in,
                                                   const int* __restrict__ samp,
                                                   float* __restrict__ dout) {
    const int i = blockIdx.x * blockDim.x + threadIdx.x;
    if (i >= NQ) return;
    const int b = i >> 11;
    const int s = samp[i] & (NPB - 1);
    const int g = b * NPB + s;
    float* qp = dout + (size_t)NQ * CD;
    qp[i * 3 + 0] = pos_in[g * 3 + 0];
    qp[i * 3 + 1] = pos_in[g * 3 + 1];
    qp[i * 3 + 2] = pos_in[g * 3 + 2];
    float* bo = qp + (size_t)NQ * 3;
    bo[i] = (float)b;
    float* io = bo + NQ;
    io[i] = (float)g;
}

extern "C" void kernel_launch(void* const* d_in, const int* in_sizes, int n_in,
                              void* d_out, int out_size, void* d_ws, size_t ws_size,
                              hipStream_t stream) {
    const float* x   = (const float*)d_in[0];
    const float* pos = (const float*)d_in[1];
    const float* W1  = (const float*)d_in[3];
    const float* b1  = (const float*)d_in[4];
    float* out = (float*)d_out;

    int* samp = (int*)d_ws;   // NQ ints = 64 KB, the ONLY workspace use

    fps_kernel<<<NB, 1024, 0, stream>>>(pos, samp);
    qmlp_kernel<<<NQ, 128, 0, stream>>>(x, pos, samp, W1, b1, out);
    tail_kernel<<<NQ / 256, 256, 0, stream>>>(pos, samp, out);
}

// Round 5
// 3097.374 us; speedup vs baseline: 1.0580x; 1.0580x over previous
//
#include <hip/hip_runtime.h>
#include <hip/hip_bf16.h>

#define NPB 8192
#define NB 8
#define MQ 2048
#define FD 64
#define KN 32
#define CD 128
#define NQ (NB*MQ)
#define CAP 512

typedef unsigned long long ull;

// exact (non-FMA) squared distance, matching ((dx*dx + dy*dy) + dz*dz) in f32
__device__ __forceinline__ float dist2(float ax, float ay, float az,
                                       float bx, float by, float bz) {
    float dx = __fsub_rn(ax, bx);
    float dy = __fsub_rn(ay, by);
    float dz = __fsub_rn(az, bz);
    return __fadd_rn(__fadd_rn(__fmul_rn(dx, dx), __fmul_rn(dy, dy)), __fmul_rn(dz, dz));
}

// ---------------- FPS: one block per cloud, 1024 threads, 8 pts/thread ----------------
// Single barrier per iteration: per-wave shfl reduce -> 16 partials in LDS
// (double-buffered) -> barrier -> ALL threads redundantly reduce partials.
__global__ __launch_bounds__(1024) void fps_kernel(const float* __restrict__ pos_in,
                                                   int* __restrict__ samp) {
    const int b = blockIdx.x;
    const int tid = threadIdx.x;
    const int wv = tid >> 6, lane = tid & 63;
    __shared__ float sx[NPB], sy[NPB], sz[NPB];   // 96 KB
    __shared__ ull part[2][16];

    float px[8], py[8], pz[8], dmin[8];
    const float* p0 = pos_in + (size_t)b * NPB * 3;
    #pragma unroll
    for (int j = 0; j < 8; j++) {
        int p = j * 1024 + tid;
        float x = p0[p * 3 + 0];
        float y = p0[p * 3 + 1];
        float z = p0[p * 3 + 2];
        sx[p] = x; sy[p] = y; sz[p] = z;
        px[j] = x; py[j] = y; pz[j] = z;
        dmin[j] = INFINITY;
    }
    __syncthreads();

    int last = 0;
    for (int t = 0; t < MQ; t++) {
        if (tid == 0) samp[b * MQ + t] = last;
        float lx = sx[last], ly = sy[last], lz = sz[last];
        float bd = -1.0f;
        int bi = 0;
        #pragma unroll
        for (int j = 0; j < 8; j++) {
            float d = dist2(px[j], py[j], pz[j], lx, ly, lz);
            float dm = fminf(dmin[j], d);
            dmin[j] = dm;
            if (dm > bd) { bd = dm; bi = j * 1024 + tid; }  // strict >: lowest idx on tie
        }
        // key: max dmin, tie -> lowest index (via ~idx); dmin >= 0 so float bits monotonic
        ull key = ((ull)__float_as_uint(bd) << 32) | (unsigned int)(~bi);
        #pragma unroll
        for (int off = 32; off; off >>= 1) {
            ull o = __shfl_down(key, (unsigned)off, 64);
            key = (o > key) ? o : key;
        }
        if (lane == 0) part[t & 1][wv] = key;
        __syncthreads();
        ull best = part[t & 1][0];
        #pragma unroll
        for (int i = 1; i < 16; i++) {
            ull o = part[t & 1][i];
            best = (o > best) ? o : best;
        }
        last = ((int)(~((unsigned int)best))) & (NPB - 1);
    }
}

// -------- Fused ball query + PointNet conv + maxpool: one block (128 thr) per query --------
__global__ __launch_bounds__(128) void qmlp_kernel(const float* __restrict__ xin,
                                                   const float* __restrict__ pos_in,
                                                   const int* __restrict__ samp,
                                                   const float* __restrict__ W1,
                                                   const float* __restrict__ b1,
                                                   float* __restrict__ out0) {
    const int q = blockIdx.x;
    const int tid = threadIdx.x;
    const int b = q >> 11;                       // q / MQ
    const float* P = pos_in + (size_t)b * NPB * 3;

    __shared__ ull buf[CAP];
    __shared__ int scnt;
    __shared__ int nb[KN];
    __shared__ __align__(16) float msg[KN][68];

    const int s = samp[q] & (NPB - 1);
    const float qx = P[s * 3 + 0];
    const float qy = P[s * 3 + 1];
    const float qz = P[s * 3 + 2];
    const float RR = (float)(0.1 * 0.1);

    if (tid == 0) scnt = 0;
    __syncthreads();

    // ---- collect candidates within radius ----
    for (int p = tid; p < NPB; p += 128) {
        float x = P[p * 3 + 0];
        float y = P[p * 3 + 1];
        float z = P[p * 3 + 2];
        float d2 = dist2(qx, qy, qz, x, y, z);
        if (d2 <= RR) {
            int slot = atomicAdd(&scnt, 1);
            if (slot < CAP) {
                buf[slot] = ((ull)__float_as_uint(d2) << 32) | (unsigned int)p;
            }
        }
    }
    __syncthreads();

    int n = scnt; if (n > CAP) n = CAP;
    const int nk = (n < KN) ? n : KN;

    if (n <= 64) {
        // ---- fast path: full bitonic sort of 64 u64 keys in wave 0 ----
        if (tid < 64) {
            ull key = (tid < n) ? buf[tid] : ~0ULL;
            #pragma unroll
            for (int k = 2; k <= 64; k <<= 1) {
                #pragma unroll
                for (int j = k >> 1; j > 0; j >>= 1) {
                    ull o = __shfl_xor(key, (unsigned)j, 64);
                    bool ascending = ((tid & k) == 0);
                    bool upper = ((tid & j) != 0);
                    bool keepMin = (ascending != upper);
                    ull mn = (o < key) ? o : key;
                    ull mx = (o < key) ? key : o;
                    key = keepMin ? mn : mx;
                }
            }
            if (tid < nk) nb[tid] = ((int)(unsigned int)key) & (NPB - 1);
        }
    } else {
        // ---- slow path (rare): 32 rounds of wave-min selection ----
        if (tid < 64) {
            ull ck[CAP / 64];
            #pragma unroll
            for (int i = 0; i < CAP / 64; i++) {
                int sl = tid + i * 64;
                ck[i] = (sl < n) ? buf[sl] : ~0ULL;
            }
            for (int r = 0; r < nk; r++) {
                ull lm = ck[0];
                int li = 0;
                #pragma unroll
                for (int i = 1; i < CAP / 64; i++) {
                    if (ck[i] < lm) { lm = ck[i]; li = i; }
                }
                ull gm = lm;
                #pragma unroll
                for (int off = 1; off < 64; off <<= 1) {
                    ull o = __shfl_xor(gm, off, 64);
                    gm = (o < gm) ? o : gm;
                }
                ull won = __ballot(lm == gm);
                int wlane = __ffsll((long long)won) - 1;
                if (tid == wlane) ck[li] = ~0ULL;
                if (tid == 0) nb[r] = ((int)(unsigned int)gm) & (NPB - 1);
            }
        }
    }
    __syncthreads();

    // ---- stage msg = [x_j (64), pos_j - pos_i (3), 0] into LDS ----
    const int lane64 = tid & 63, half = tid >> 6;
    for (int k = half; k < nk; k += 2) {
        int p = nb[k];
        msg[k][lane64] = xin[((size_t)(b * NPB + p)) * FD + lane64];
    }
    if (tid < nk) {   // nk <= 32 <= 128
        int p = nb[tid];
        msg[tid][64] = __fsub_rn(P[p * 3 + 0], qx);
        msg[tid][65] = __fsub_rn(P[p * 3 + 1], qy);
        msg[tid][66] = __fsub_rn(P[p * 3 + 2], qz);
        msg[tid][67] = 0.0f;
    }

    // ---- per-thread output channel ----
    float w[68];
    #pragma unroll
    for (int f = 0; f < 67; f++) w[f] = W1[f * CD + tid];
    w[67] = 0.0f;
    const float bias = b1[tid];
    __syncthreads();

    float acc = 0.0f;  // relu >= 0 and nk >= 1 (self), so 0 is identity for the max
    for (int k = 0; k < nk; k++) {
        float s0 = 0.f, s1 = 0.f, s2 = 0.f, s3 = 0.f;
        #pragma unroll
        for (int f4 = 0; f4 < 17; f4++) {
            float4 mv = *(const float4*)&msg[k][f4 * 4];
            s0 = fmaf(mv.x, w[f4 * 4 + 0], s0);
            s1 = fmaf(mv.y, w[f4 * 4 + 1], s1);
            s2 = fmaf(mv.z, w[f4 * 4 + 2], s2);
            s3 = fmaf(mv.w, w[f4 * 4 + 3], s3);
        }
        float h = (s0 + s1) + (s2 + s3) + bias;
        h = fmaxf(h, 0.0f);
        acc = fmaxf(acc, h);
    }
    out0[(size_t)q * CD + tid] = acc;
}

// ---------------- qpos / batch / idx outputs (all float32) ----------------
__global__ __launch_bounds__(256) void tail_kernel(const float* __restrict__ pos_in,
                                                   const int* __restrict__ samp,
                                                   float* __restrict__ dout) {
    const int i = blockIdx.x * blockDim.x + threadIdx.x;
    if (i >= NQ) return;
    const int b = i >> 11;
    const int s = samp[i] & (NPB - 1);
    const int g = b * NPB + s;
    float* qp = dout + (size_t)NQ * CD;
    qp[i * 3 + 0] = pos_in[g * 3 + 0];
    qp[i * 3 + 1] = pos_in[g * 3 + 1];
    qp[i * 3 + 2] = pos_in[g * 3 + 2];
    float* bo = qp + (size_t)NQ * 3;
    bo[i] = (float)b;
    float* io = bo + NQ;
    io[i] = (float)g;
}

extern "C" void kernel_launch(void* const* d_in, const int* in_sizes, int n_in,
                              void* d_out, int out_size, void* d_ws, size_t ws_size,
                              hipStream_t stream) {
    const float* x   = (const float*)d_in[0];
    const float* pos = (const float*)d_in[1];
    const float* W1  = (const float*)d_in[3];
    const float* b1  = (const float*)d_in[4];
    float* out = (float*)d_out;

    int* samp = (int*)d_ws;   // NQ ints = 64 KB, the ONLY workspace use

    fps_kernel<<<NB, 1024, 0, stream>>>(pos, samp);
    qmlp_kernel<<<NQ, 128, 0, stream>>>(x, pos, samp, W1, b1, out);
    tail_kernel<<<NQ / 256, 256, 0, stream>>>(pos, samp, out);
}

// Round 6
// 2803.656 us; speedup vs baseline: 1.1688x; 1.1048x over previous
//
#include <hip/hip_runtime.h>
#include <hip/hip_bf16.h>

#define NPB 8192
#define NB 8
#define MQ 2048
#define FD 64
#define KN 32
#define CD 128
#define NQ (NB*MQ)
#define CAP 512
#define NCB 248                               // consumer blocks
#define NUNITS (NCB*4)                        // 992 units of 128 threads
#define QITERS ((NQ + NUNITS - 1) / NUNITS)   // 17

typedef unsigned long long ull;

// exact (non-FMA) squared distance, matching ((dx*dx + dy*dy) + dz*dz) in f32
__device__ __forceinline__ float dist2(float ax, float ay, float az,
                                       float bx, float by, float bz) {
    float dx = __fsub_rn(ax, bx);
    float dy = __fsub_rn(ay, by);
    float dz = __fsub_rn(az, bz);
    return __fadd_rn(__fadd_rn(__fmul_rn(dx, dx), __fmul_rn(dy, dy)), __fmul_rn(dz, dz));
}

// 6-step full-wave (64-lane) u64 max reduce via DPP; result valid in lane 63.
// Identity is 0 (keys are non-negative); invalid-source lanes keep old=0.
__device__ __forceinline__ ull dpp_max_u64(ull key) {
#define DPP_STEP(CTRL)                                                          \
    {                                                                           \
        int lo = (int)(unsigned)key, hi = (int)(key >> 32);                     \
        int lo2 = __builtin_amdgcn_update_dpp(0, lo, CTRL, 0xf, 0xf, false);    \
        int hi2 = __builtin_amdgcn_update_dpp(0, hi, CTRL, 0xf, 0xf, false);    \
        ull o = ((ull)(unsigned)hi2 << 32) | (unsigned)lo2;                     \
        if (o > key) key = o;                                                   \
    }
    DPP_STEP(0x111)  // row_shr:1
    DPP_STEP(0x112)  // row_shr:2
    DPP_STEP(0x114)  // row_shr:4
    DPP_STEP(0x118)  // row_shr:8  -> lane 15 of each row has row max
    DPP_STEP(0x142)  // row_bcast15 -> lane 31 = rows0-1 max, lane 63 = rows2-3 max
    DPP_STEP(0x143)  // row_bcast31 -> lane 63 = full-wave max
#undef DPP_STEP
    return key;
}

struct FpsSM {
    float sx[NPB], sy[NPB], sz[NPB];   // 96 KB
    ull slot[3];
};
struct UnitSM {
    float msg[KN][68];                 // 8704 B, 16-aligned (first member)
    ull buf[CAP];                      // 4096 B
    int nb[KN];
    int scnt;
    int pad;
};
union SMU {
    FpsSM f;
    UnitSM u[4];
};

__global__ __launch_bounds__(512) void mega_kernel(const float* __restrict__ xin,
                                                   const float* __restrict__ pos,
                                                   const float* __restrict__ W1,
                                                   const float* __restrict__ b1,
                                                   int* __restrict__ samp,
                                                   int* __restrict__ progress,
                                                   float* __restrict__ out) {
    __shared__ SMU sm;
    const int tid = threadIdx.x;

    if (blockIdx.x < NB) {
        // ======================= FPS producer (blocks 0..7) =======================
        const int b = blockIdx.x;
        const float* p0 = pos + (size_t)b * NPB * 3;
        float px[16], py[16], pz[16], dmin[16];
        #pragma unroll
        for (int j = 0; j < 16; j++) {
            int p = j * 512 + tid;
            float xx = p0[p * 3 + 0];
            float yy = p0[p * 3 + 1];
            float zz = p0[p * 3 + 2];
            sm.f.sx[p] = xx; sm.f.sy[p] = yy; sm.f.sz[p] = zz;
            px[j] = xx; py[j] = yy; pz[j] = zz;
            dmin[j] = INFINITY;
        }
        if (tid < 3) sm.f.slot[tid] = 0;
        __syncthreads();

        int last = 0;
        for (int t = 0; t < MQ; t++) {
            if (tid == 0) {
                samp[b * MQ + t] = last;
                if ((t & 7) == 7)   // publish in batches of 8 (2047&7==7 covers the end)
                    __hip_atomic_store(&progress[b], t + 1, __ATOMIC_RELEASE,
                                       __HIP_MEMORY_SCOPE_AGENT);
            }
            float lx = sm.f.sx[last], ly = sm.f.sy[last], lz = sm.f.sz[last];
            float bd = -1.0f;
            int bi = 0;
            #pragma unroll
            for (int j = 0; j < 16; j++) {
                float d = dist2(px[j], py[j], pz[j], lx, ly, lz);
                float dm = fminf(dmin[j], d);
                dmin[j] = dm;
                if (dm > bd) { bd = dm; bi = j * 512 + tid; }  // strict >: lowest idx on tie
            }
            // key: max dmin, tie -> lowest index (via ~idx); dmin >= 0 so bits monotonic
            ull key = ((ull)__float_as_uint(bd) << 32) | (unsigned)(~bi);
            key = dpp_max_u64(key);
            if ((tid & 63) == 63) atomicMax(&sm.f.slot[t % 3], key);
            if (tid == 0) sm.f.slot[(t + 1) % 3] = 0;   // reset-ahead (consumed 2 barriers ago)
            __syncthreads();
            last = ((int)(~(unsigned)sm.f.slot[t % 3])) & (NPB - 1);
        }
        return;
    }

    // ================== consumers: ball query + MLP + tail outputs ==================
    const int c = blockIdx.x - NB;         // 0..247
    const int unit = tid >> 7;             // 0..3
    const int ut = tid & 127;              // thread-in-unit
    UnitSM& U = sm.u[unit];
    const int g = c * 4 + unit;            // global unit id, 0..991
    const float RR = (float)(0.1 * 0.1);

    // per-channel weights, hoisted across queries
    float w[68];
    #pragma unroll
    for (int f = 0; f < 67; f++) w[f] = W1[f * CD + ut];
    w[67] = 0.0f;
    const float bias = b1[ut];

    for (int qi = 0; qi < QITERS; qi++) {
        const int q = g + qi * NUNITS;
        const bool active = q < NQ;
        int b = 0, s = 0;
        const float* P = pos;
        float qx = 0.f, qy = 0.f, qz = 0.f;

        if (active) {
            b = q >> 11;
            const int tq = q & (MQ - 1);
            while (__hip_atomic_load(&progress[b], __ATOMIC_ACQUIRE,
                                     __HIP_MEMORY_SCOPE_AGENT) < tq + 1)
                __builtin_amdgcn_s_sleep(16);
            s = samp[q] & (NPB - 1);
            P = pos + (size_t)b * NPB * 3;
            qx = P[s * 3 + 0]; qy = P[s * 3 + 1]; qz = P[s * 3 + 2];
        }
        if (ut == 0) U.scnt = 0;
        __syncthreads();                                   // barrier 1

        if (active) {
            for (int p = ut; p < NPB; p += 128) {
                float xx = P[p * 3 + 0];
                float yy = P[p * 3 + 1];
                float zz = P[p * 3 + 2];
                float d2v = dist2(qx, qy, qz, xx, yy, zz);
                if (d2v <= RR) {
                    int slot = atomicAdd(&U.scnt, 1);
                    if (slot < CAP)
                        U.buf[slot] = ((ull)__float_as_uint(d2v) << 32) | (unsigned)p;
                }
            }
        }
        __syncthreads();                                   // barrier 2

        int n = 0, nk = 0;
        if (active) {
            n = U.scnt; if (n > CAP) n = CAP;
            nk = (n < KN) ? n : KN;
        }
        if (active && ut < 64) {
            if (n <= 64) {
                // fast path: 64-key bitonic sort in the unit's first wave
                ull key = (ut < n) ? U.buf[ut] : ~0ULL;
                #pragma unroll
                for (int k = 2; k <= 64; k <<= 1) {
                    #pragma unroll
                    for (int j = k >> 1; j > 0; j >>= 1) {
                        ull o = __shfl_xor(key, (unsigned)j, 64);
                        bool ascending = ((ut & k) == 0);
                        bool upper = ((ut & j) != 0);
                        bool keepMin = (ascending != upper);
                        ull mn = (o < key) ? o : key;
                        ull mx = (o < key) ? key : o;
                        key = keepMin ? mn : mx;
                    }
                }
                if (ut < nk) U.nb[ut] = ((int)(unsigned)key) & (NPB - 1);
            } else {
                // slow path (rare): nk rounds of wave-min selection
                ull ck[CAP / 64];
                #pragma unroll
                for (int i = 0; i < CAP / 64; i++) {
                    int sl = ut + i * 64;
                    ck[i] = (sl < n) ? U.buf[sl] : ~0ULL;
                }
                for (int r = 0; r < nk; r++) {
                    ull lm = ck[0];
                    int li = 0;
                    #pragma unroll
                    for (int i = 1; i < CAP / 64; i++) {
                        if (ck[i] < lm) { lm = ck[i]; li = i; }
                    }
                    ull gm = lm;
                    #pragma unroll
                    for (int off = 1; off < 64; off <<= 1) {
                        ull o = __shfl_xor(gm, off, 64);
                        gm = (o < gm) ? o : gm;
                    }
                    ull won = __ballot(lm == gm);
                    int wlane = __ffsll((long long)won) - 1;
                    if (ut == wlane) ck[li] = ~0ULL;
                    if (ut == 0) U.nb[r] = ((int)(unsigned)gm) & (NPB - 1);
                }
            }
        }
        __syncthreads();                                   // barrier 3

        if (active) {
            const int lane64 = ut & 63, half = ut >> 6;
            for (int k = half; k < nk; k += 2) {
                int p = U.nb[k];
                U.msg[k][lane64] = xin[((size_t)(b * NPB + p)) * FD + lane64];
            }
            if (ut < nk) {
                int p = U.nb[ut];
                U.msg[ut][64] = __fsub_rn(P[p * 3 + 0], qx);
                U.msg[ut][65] = __fsub_rn(P[p * 3 + 1], qy);
                U.msg[ut][66] = __fsub_rn(P[p * 3 + 2], qz);
                U.msg[ut][67] = 0.0f;
            }
        }
        __syncthreads();                                   // barrier 4

        if (active) {
            float acc = 0.0f;   // relu >= 0 and nk >= 1 (self), so 0 is the max identity
            for (int k = 0; k < nk; k++) {
                float s0 = 0.f, s1 = 0.f, s2 = 0.f, s3 = 0.f;
                #pragma unroll
                for (int f4 = 0; f4 < 17; f4++) {
                    float4 mv = *(const float4*)&U.msg[k][f4 * 4];
                    s0 = fmaf(mv.x, w[f4 * 4 + 0], s0);
                    s1 = fmaf(mv.y, w[f4 * 4 + 1], s1);
                    s2 = fmaf(mv.z, w[f4 * 4 + 2], s2);
                    s3 = fmaf(mv.w, w[f4 * 4 + 3], s3);
                }
                float h = (s0 + s1) + (s2 + s3) + bias;
                h = fmaxf(h, 0.0f);
                acc = fmaxf(acc, h);
            }
            out[(size_t)q * CD + ut] = acc;
            if (ut == 0) {
                float* qp = out + (size_t)NQ * CD;
                qp[q * 3 + 0] = qx;
                qp[q * 3 + 1] = qy;
                qp[q * 3 + 2] = qz;
                float* bo = qp + (size_t)NQ * 3;
                bo[q] = (float)b;
                float* io = bo + NQ;
                io[q] = (float)(b * NPB + s);
            }
        }
    }
}

extern "C" void kernel_launch(void* const* d_in, const int* in_sizes, int n_in,
                              void* d_out, int out_size, void* d_ws, size_t ws_size,
                              hipStream_t stream) {
    const float* x   = (const float*)d_in[0];
    const float* pos = (const float*)d_in[1];
    const float* W1  = (const float*)d_in[3];
    const float* b1  = (const float*)d_in[4];
    float* out = (float*)d_out;

    int* samp = (int*)d_ws;              // NQ ints
    int* progress = samp + NQ;           // NB ints

    hipMemsetAsync(progress, 0, NB * sizeof(int), stream);
    mega_kernel<<<NB + NCB, 512, 0, stream>>>(x, pos, W1, b1, samp, progress, out);
}

// Round 8
// 2476.334 us; speedup vs baseline: 1.3233x; 1.1322x over previous
//
#include <hip/hip_runtime.h>
#include <hip/hip_bf16.h>

#define NPB 8192
#define NB 8
#define MQ 2048
#define FD 64
#define KN 32
#define CD 128
#define NQ (NB*MQ)
#define CAP 512
#define NCB 248                               // consumer blocks
#define NUNITS (NCB*4)                        // 992 units of 128 threads
#define QITERS ((NQ + NUNITS - 1) / NUNITS)   // 17

typedef unsigned long long ull;

// exact (non-FMA) squared distance, matching ((dx*dx + dy*dy) + dz*dz) in f32
__device__ __forceinline__ float dist2(float ax, float ay, float az,
                                       float bx, float by, float bz) {
    float dx = __fsub_rn(ax, bx);
    float dy = __fsub_rn(ay, by);
    float dz = __fsub_rn(az, bz);
    return __fadd_rn(__fadd_rn(__fmul_rn(dx, dx), __fmul_rn(dy, dy)), __fmul_rn(dz, dz));
}

// 6-step full-wave (64-lane) u64 max reduce via DPP; result valid in lane 63.
// Identity is 0 (keys are non-negative); invalid-source lanes keep old=0.
// (bit-correctness HW-verified in round 6: idx output was exact)
__device__ __forceinline__ ull dpp_max_u64(ull key) {
#define DPP_STEP(CTRL)                                                          \
    {                                                                           \
        int lo = (int)(unsigned)key, hi = (int)(key >> 32);                     \
        int lo2 = __builtin_amdgcn_update_dpp(0, lo, CTRL, 0xf, 0xf, false);    \
        int hi2 = __builtin_amdgcn_update_dpp(0, hi, CTRL, 0xf, 0xf, false);    \
        ull o = ((ull)(unsigned)hi2 << 32) | (unsigned)lo2;                     \
        if (o > key) key = o;                                                   \
    }
    DPP_STEP(0x111)  // row_shr:1
    DPP_STEP(0x112)  // row_shr:2
    DPP_STEP(0x114)  // row_shr:4
    DPP_STEP(0x118)  // row_shr:8  -> lane 15 of each row has row max
    DPP_STEP(0x142)  // row_bcast15 -> lane 31 = rows0-1 max, lane 63 = rows2-3 max
    DPP_STEP(0x143)  // row_bcast31 -> lane 63 = full-wave max
#undef DPP_STEP
    return key;
}

// ---------- presort: per cloud, sort point indices by 8^3 grid cell ----------
__global__ __launch_bounds__(512) void presort_kernel(const float* __restrict__ pos,
                                                      unsigned int* __restrict__ sorted) {
    __shared__ unsigned int skeys[NPB];    // 32 KB only
    const int b = blockIdx.x;
    const int tid = threadIdx.x;
    const float* p0 = pos + (size_t)b * NPB * 3;
    for (int i = tid; i < NPB; i += 512) {
        float x = p0[i * 3 + 0];
        float y = p0[i * 3 + 1];
        float z = p0[i * 3 + 2];
        int cx = min(7, max(0, (int)(x * 8.0f)));
        int cy = min(7, max(0, (int)(y * 8.0f)));
        int cz = min(7, max(0, (int)(z * 8.0f)));
        unsigned cell = ((unsigned)cz << 6) | ((unsigned)cy << 3) | (unsigned)cx;
        skeys[i] = (cell << 13) | (unsigned)i;
    }
    __syncthreads();
    for (unsigned k = 2; k <= NPB; k <<= 1) {
        for (unsigned j = k >> 1; j > 0; j >>= 1) {
            for (unsigned i = tid; i < NPB / 2; i += 512) {
                unsigned a = ((i & ~(j - 1)) << 1) | (i & (j - 1));
                unsigned c = a | j;
                unsigned x = skeys[a], y = skeys[c];
                bool up = ((a & k) == 0);
                if ((x > y) == up) { skeys[a] = y; skeys[c] = x; }
            }
            __syncthreads();
        }
    }
    for (int i = tid; i < NPB; i += 512)
        sorted[b * NPB + i] = skeys[i] & (NPB - 1);
}

struct FpsSM {
    float sx[NPB], sy[NPB], sz[NPB];   // 96 KB, ORIGINAL index order
    ull part[2][8];                    // double-buffered wave partials
};
struct UnitSM {
    float msg[KN][68];                 // 8704 B, 16-aligned (first member)
    ull buf[CAP];                      // 4096 B
    int nb[KN];
    int scnt;
    int pad;
};
union SMU {
    FpsSM f;
    UnitSM u[4];
};

__global__ __launch_bounds__(512) void mega_kernel(const float* __restrict__ xin,
                                                   const float* __restrict__ pos,
                                                   const float* __restrict__ W1,
                                                   const float* __restrict__ b1,
                                                   const unsigned int* __restrict__ sorted,
                                                   int* __restrict__ samp,
                                                   int* __restrict__ progress,
                                                   float* __restrict__ out) {
    __shared__ SMU sm;
    const int tid = threadIdx.x;

    if (blockIdx.x < NB) {
        // ======================= FPS producer (blocks 0..7) =======================
        const int b = blockIdx.x;
        const int wv = tid >> 6, lane = tid & 63;
        const float* p0 = pos + (size_t)b * NPB * 3;

        for (int i = tid; i < NPB; i += 512) {
            sm.f.sx[i] = p0[i * 3 + 0];
            sm.f.sy[i] = p0[i * 3 + 1];
            sm.f.sz[i] = p0[i * 3 + 2];
        }
        __syncthreads();

        // ---- each thread takes 16 spatially-contiguous points into registers ----
        const unsigned int* sp = sorted + b * NPB + tid * 16;
        float px[16], py[16], pz[16], dmin[16];
        unsigned orig[16];
        float bx0 = __builtin_huge_valf(), bx1 = -__builtin_huge_valf();
        float by0 = __builtin_huge_valf(), by1 = -__builtin_huge_valf();
        float bz0 = __builtin_huge_valf(), bz1 = -__builtin_huge_valf();
        #pragma unroll
        for (int j = 0; j < 16; j++) {
            unsigned o = sp[j] & (NPB - 1);
            orig[j] = o;
            float x = sm.f.sx[o], y = sm.f.sy[o], z = sm.f.sz[o];
            px[j] = x; py[j] = y; pz[j] = z;
            dmin[j] = __builtin_huge_valf();
            bx0 = fminf(bx0, x); bx1 = fmaxf(bx1, x);
            by0 = fminf(by0, y); by1 = fmaxf(by1, y);
            bz0 = fminf(bz0, z); bz1 = fmaxf(bz1, z);
        }
        ull mykey = ((ull)0x7f800000u << 32);   // dmin part = +INF -> scans at t=0
        __syncthreads();

        for (int t = 0; t < MQ; t++) {
            int last;
            if (t) {
                const ull* pp = sm.f.part[(t - 1) & 1];
                ull g = pp[0];
                #pragma unroll
                for (int i = 1; i < 8; i++) { ull o = pp[i]; g = (o > g) ? o : g; }
                last = ((int)(~(unsigned)g)) & (NPB - 1);
            } else {
                last = 0;
            }
            if (tid == 0) {
                samp[b * MQ + t] = last;
                if ((t & 7) == 7)   // publish in batches of 8 (2047&7==7 covers the end)
                    __hip_atomic_store(&progress[b], t + 1, __ATOMIC_RELEASE,
                                       __HIP_MEMORY_SCOPE_AGENT);
            }
            float lx = sm.f.sx[last], ly = sm.f.sy[last], lz = sm.f.sz[last];

            // conservative lower bound of d2(last, any point in this thread's bbox)
            float ddx = fmaxf(fmaxf(bx0 - lx, lx - bx1), 0.0f);
            float ddy = fmaxf(fmaxf(by0 - ly, ly - by1), 0.0f);
            float ddz = fmaxf(fmaxf(bz0 - lz, lz - bz1), 0.0f);
            float dlb = ddx * ddx + ddy * ddy + ddz * ddz;
            float cm = __uint_as_float((unsigned)(mykey >> 32));

            if (__fmul_rn(0.999f, dlb) < cm) {
                ull bestk = 0;
                #pragma unroll
                for (int j = 0; j < 16; j++) {
                    float d = dist2(px[j], py[j], pz[j], lx, ly, lz);
                    float dm = fminf(dmin[j], d);
                    dmin[j] = dm;
                    ull kj = ((ull)__float_as_uint(dm) << 32) | (unsigned)(~orig[j]);
                    if (kj > bestk) bestk = kj;
                }
                mykey = bestk;
            }
            ull w = dpp_max_u64(mykey);
            if (lane == 63) sm.f.part[t & 1][wv] = w;
            __syncthreads();
        }
        return;
    }

    // ================== consumers: ball query + MLP + tail outputs ==================
    const int c = blockIdx.x - NB;         // 0..247
    const int unit = tid >> 7;             // 0..3
    const int ut = tid & 127;              // thread-in-unit
    UnitSM& U = sm.u[unit];
    const int g = c * 4 + unit;            // global unit id, 0..991
    const float RR = (float)(0.1 * 0.1);

    // per-channel weights, hoisted across queries
    float w[68];
    #pragma unroll
    for (int f = 0; f < 67; f++) w[f] = W1[f * CD + ut];
    w[67] = 0.0f;
    const float bias = b1[ut];

    for (int qi = 0; qi < QITERS; qi++) {
        const int q = g + qi * NUNITS;
        const bool active = q < NQ;
        int b = 0, s = 0;
        const float* P = pos;
        float qx = 0.f, qy = 0.f, qz = 0.f;

        if (active) {
            b = q >> 11;
            const int tq = q & (MQ - 1);
            while (__hip_atomic_load(&progress[b], __ATOMIC_ACQUIRE,
                                     __HIP_MEMORY_SCOPE_AGENT) < tq + 1)
                __builtin_amdgcn_s_sleep(16);
            s = samp[q] & (NPB - 1);
            P = pos + (size_t)b * NPB * 3;
            qx = P[s * 3 + 0]; qy = P[s * 3 + 1]; qz = P[s * 3 + 2];
        }
        if (ut == 0) U.scnt = 0;
        __syncthreads();                                   // barrier 1

        if (active) {
            for (int p = ut; p < NPB; p += 128) {
                float xx = P[p * 3 + 0];
                float yy = P[p * 3 + 1];
                float zz = P[p * 3 + 2];
                float d2v = dist2(qx, qy, qz, xx, yy, zz);
                if (d2v <= RR) {
                    int slot = atomicAdd(&U.scnt, 1);
                    if (slot < CAP)
                        U.buf[slot] = ((ull)__float_as_uint(d2v) << 32) | (unsigned)p;
                }
            }
        }
        __syncthreads();                                   // barrier 2

        int n = 0, nk = 0;
        if (active) {
            n = U.scnt; if (n > CAP) n = CAP;
            nk = (n < KN) ? n : KN;
        }
        if (active && ut < 64) {
            if (n <= 64) {
                // fast path: 64-key bitonic sort in the unit's first wave
                ull key = (ut < n) ? U.buf[ut] : ~0ULL;
                #pragma unroll
                for (int k = 2; k <= 64; k <<= 1) {
                    #pragma unroll
                    for (int j = k >> 1; j > 0; j >>= 1) {
                        ull o = __shfl_xor(key, (unsigned)j, 64);
                        bool ascending = ((ut & k) == 0);
                        bool upper = ((ut & j) != 0);
                        bool keepMin = (ascending != upper);
                        ull mn = (o < key) ? o : key;
                        ull mx = (o < key) ? key : o;
                        key = keepMin ? mn : mx;
                    }
                }
                if (ut < nk) U.nb[ut] = ((int)(unsigned)key) & (NPB - 1);
            } else {
                // slow path (rare): nk rounds of wave-min selection
                ull ck[CAP / 64];
                #pragma unroll
                for (int i = 0; i < CAP / 64; i++) {
                    int sl = ut + i * 64;
                    ck[i] = (sl < n) ? U.buf[sl] : ~0ULL;
                }
                for (int r = 0; r < nk; r++) {
                    ull lm = ck[0];
                    int li = 0;
                    #pragma unroll
                    for (int i = 1; i < CAP / 64; i++) {
                        if (ck[i] < lm) { lm = ck[i]; li = i; }
                    }
                    ull gm = lm;
                    #pragma unroll
                    for (int off = 1; off < 64; off <<= 1) {
                        ull o = __shfl_xor(gm, off, 64);
                        gm = (o < gm) ? o : gm;
                    }
                    ull won = __ballot(lm == gm);
                    int wlane = __ffsll((long long)won) - 1;
                    if (ut == wlane) ck[li] = ~0ULL;
                    if (ut == 0) U.nb[r] = ((int)(unsigned)gm) & (NPB - 1);
                }
            }
        }
        __syncthreads();                                   // barrier 3

        if (active) {
            const int lane64 = ut & 63, half = ut >> 6;
            for (int k = half; k < nk; k += 2) {
                int p = U.nb[k];
                U.msg[k][lane64] = xin[((size_t)(b * NPB + p)) * FD + lane64];
            }
            if (ut < nk) {
                int p = U.nb[ut];
                U.msg[ut][64] = __fsub_rn(P[p * 3 + 0], qx);
                U.msg[ut][65] = __fsub_rn(P[p * 3 + 1], qy);
                U.msg[ut][66] = __fsub_rn(P[p * 3 + 2], qz);
                U.msg[ut][67] = 0.0f;
            }
        }
        __syncthreads();                                   // barrier 4

        if (active) {
            float acc = 0.0f;   // relu >= 0 and nk >= 1 (self), so 0 is the max identity
            for (int k = 0; k < nk; k++) {
                float s0 = 0.f, s1 = 0.f, s2 = 0.f, s3 = 0.f;
                #pragma unroll
                for (int f4 = 0; f4 < 17; f4++) {
                    float4 mv = *(const float4*)&U.msg[k][f4 * 4];
                    s0 = fmaf(mv.x, w[f4 * 4 + 0], s0);
                    s1 = fmaf(mv.y, w[f4 * 4 + 1], s1);
                    s2 = fmaf(mv.z, w[f4 * 4 + 2], s2);
                    s3 = fmaf(mv.w, w[f4 * 4 + 3], s3);
                }
                float h = (s0 + s1) + (s2 + s3) + bias;
                h = fmaxf(h, 0.0f);
                acc = fmaxf(acc, h);
            }
            out[(size_t)q * CD + ut] = acc;
            if (ut == 0) {
                float* qp = out + (size_t)NQ * CD;
                qp[q * 3 + 0] = qx;
                qp[q * 3 + 1] = qy;
                qp[q * 3 + 2] = qz;
                float* bo = qp + (size_t)NQ * 3;
                bo[q] = (float)b;
                float* io = bo + NQ;
                io[q] = (float)(b * NPB + s);
            }
        }
    }
}

extern "C" void kernel_launch(void* const* d_in, const int* in_sizes, int n_in,
                              void* d_out, int out_size, void* d_ws, size_t ws_size,
                              hipStream_t stream) {
    const float* x   = (const float*)d_in[0];
    const float* pos = (const float*)d_in[1];
    const float* W1  = (const float*)d_in[3];
    const float* b1  = (const float*)d_in[4];
    float* out = (float*)d_out;

    int* samp = (int*)d_ws;                     // NQ ints
    int* progress = samp + NQ;                  // NB ints
    unsigned int* sorted = (unsigned int*)(progress + NB);   // NB*NPB u32

    hipMemsetAsync(progress, 0, NB * sizeof(int), stream);
    presort_kernel<<<NB, 512, 0, stream>>>(pos, sorted);
    mega_kernel<<<NB + NCB, 512, 0, stream>>>(x, pos, W1, b1, sorted, samp, progress, out);
}